// Round 10
// baseline (429.264 us; speedup 1.0000x reference)
//
#include <hip/hip_runtime.h>

typedef _Float16 h16;
typedef _Float16 h16x2 __attribute__((ext_vector_type(2)));
typedef _Float16 h16x4 __attribute__((ext_vector_type(4)));
typedef _Float16 h16x8 __attribute__((ext_vector_type(8)));
typedef float f32x4 __attribute__((ext_vector_type(4)));

#if __has_builtin(__builtin_amdgcn_fdot2)
#define FDOT2(a, b, c) __builtin_amdgcn_fdot2((a), (b), (c), false)
#else
static __device__ __forceinline__ float FDOT2(h16x2 a, h16x2 b, float c) {
  return c + (float)a[0] * (float)b[0] + (float)a[1] * (float)b[1];
}
#endif

// ---- problem constants ----
#define N_IMG 512      // B*C = 8*64
#define C_CH  64
#define H_IN  512
#define W_IN  512
#define NC    259      // subband extent
#define PITP  528      // h16 per interleaved row: 264 (LH,HL) pairs
#define S2    ((size_t)NC * PITP)
#define GPIT  264
#define RING  38       // LDS ring rows in k_fwd

constexpr float DLO[8] = {
  -0.010597401784997278f,  0.032883011666982945f,  0.030841381835986965f, -0.18703481171888114f,
  -0.02798376941698385f,   0.6308807679295904f,    0.7148465705525415f,    0.23037781330885523f};
constexpr float DHI[8] = {
  -0.23037781330885523f,   0.7148465705525415f,   -0.6308807679295904f,   -0.02798376941698385f,
   0.18703481171888114f,   0.030841381835986965f, -0.032883011666982945f, -0.010597401784997278f};
constexpr float RLO[8] = {
   0.23037781330885523f,   0.7148465705525415f,    0.6308807679295904f,   -0.02798376941698385f,
  -0.18703481171888114f,   0.030841381835986965f,  0.032883011666982945f, -0.010597401784997278f};
constexpr float RHI[8] = {
  -0.010597401784997278f, -0.032883011666982945f,  0.030841381835986965f,  0.18703481171888114f,
  -0.02798376941698385f,  -0.6308807679295904f,    0.7148465705525415f,   -0.23037781330885523f};

// =====================================================================
// Kernel 1: persistent half-image blocks. 38-row LDS ring carries the
// row-DWT halo between 16-row iterations (x read ~1.02x). Packed-fp16
// column DWT -> interleaved (LH,HL). Gate stats in registers.
// =====================================================================
__global__ __launch_bounds__(512) void k_fwd(const float* __restrict__ x,
                                             h16* __restrict__ wsh,
                                             float* __restrict__ stat) {
  __shared__ h16 sad[RING * PITP];           // 40,128 B -> 4 blocks/CU
  // bijective XCD swizzle: nwg = 1024 = 8 * 128
  const int p = blockIdx.x;
  const int w = (p & 7) * 128 + (p >> 3);
  const int bc = w >> 1;
  const int half = w & 1;
  const int h_begin = half ? 130 : 0;
  const int h_end = half ? 259 : 130;
  const int tid = threadIdx.x;
  const int wave = tid >> 6, lane = tid & 63;
  const float* xim = x + (size_t)bc * (H_IN * (size_t)W_IN);
  const size_t obase = (size_t)bc * S2;

  float* rsM = stat;
  float* rsS = stat + (size_t)N_IMG * 264;
  float* cpM = rsS + (size_t)N_IMG * 264;
  float* cpS = cpM + (size_t)N_IMG * 2 * 264;

  // per-lane running column stats
  float c0m[4], c0s[4], c1m[4], c1s[4];
#pragma unroll
  for (int k = 0; k < 4; ++k) {
    c0m[k] = -3.4e38f; c0s[k] = 0.f; c1m[k] = -3.4e38f; c1s[k] = 0.f;
  }

  int rx_next = 2 * h_begin - 6;
  for (int h0 = h_begin; h0 < h_end; h0 += 16) {
    const int hcount = min(16, h_end - h0);
    const int rx_hi = 2 * (h0 + hcount - 1) + 1;

    // Phase A: row DWT of new x rows into ring slots
    for (int j = rx_next + wave; j <= rx_hi; j += 8) {
      int r = j;
      r = r < 0 ? -r - 1 : (r >= H_IN ? 2 * H_IN - 1 - r : r);
      const float* xrow = xim + (size_t)r * W_IN;
      h16* sj = sad + ((j + RING) % RING) * PITP;
      const int base = lane ? 8 * lane - 8 : 0;
      const float4 q0 = *(const float4*)(xrow + base);
      const float4 q1 = *(const float4*)(xrow + base + 4);
      const float4 q2 = *(const float4*)(xrow + base + 8);
      const float4 q3 = *(const float4*)(xrow + base + 12);
      const float v[16] = {q0.x, q0.y, q0.z, q0.w, q1.x, q1.y, q1.z, q1.w,
                           q2.x, q2.y, q2.z, q2.w, q3.x, q3.y, q3.z, q3.w};
      if (lane == 0) {
        h16x8 o;
#pragma unroll
        for (int i = 0; i < 4; ++i) {
          float a = 0.f, d = 0.f;
#pragma unroll
          for (int m = 0; m < 8; ++m) {
            int pp = 2 * i + 1 - m; pp = pp < 0 ? -pp - 1 : pp;
            const float t = v[pp];
            a += DLO[m] * t; d += DHI[m] * t;
          }
          o[2 * i] = (h16)a; o[2 * i + 1] = (h16)d;
        }
        *(h16x8*)(sj) = o;
      } else {
        h16x8 o;
#pragma unroll
        for (int k = 0; k < 4; ++k) {
          float a = 0.f, d = 0.f;
#pragma unroll
          for (int m = 0; m < 8; ++m) {
            const float t = v[2 * k + 9 - m];
            a += DLO[m] * t; d += DHI[m] * t;
          }
          o[2 * k] = (h16)a; o[2 * k + 1] = (h16)d;
        }
        *(h16x8*)(sj + 8 * lane) = o;
        if (lane == 63) {
#pragma unroll
          for (int i = 256; i < 259; ++i) {
            float a = 0.f, d = 0.f;
#pragma unroll
            for (int m = 0; m < 8; ++m) {
              int pp = 2 * i + 1 - m; pp = pp >= 512 ? 1023 - pp : pp;
              const float t = v[pp - 496];
              a += DLO[m] * t; d += DHI[m] * t;
            }
            h16x2 o2; o2[0] = (h16)a; o2[1] = (h16)d;
            *(h16x2*)(sj + 2 * i) = o2;
          }
        }
      }
    }
    rx_next = rx_hi + 1;
    __syncthreads();

    // Phase B: packed column DWT; one subband row per wave (strided)
    for (int dh = wave; dh < hcount; dh += 8) {
      const int h = h0 + dh;
      const int s0 = (2 * h + 1) % RING;
      float rowm = -3.4e38f, rowsum = 0.f;
#pragma unroll
      for (int pass = 0; pass < 2; ++pass) {
        const int pq = lane + 64 * pass;
        if (pq < 66) {
          h16x2 a0 = {0, 0}, a1 = {0, 0}, a2_ = {0, 0}, a3 = {0, 0};
#pragma unroll
          for (int m = 0; m < 8; ++m) {
            int slot = s0 - m; slot = slot < 0 ? slot + RING : slot;
            const h16x8 pr = *(const h16x8*)(sad + slot * PITP + 8 * pq);
            const h16x2 cf = {(h16)DHI[m], (h16)DLO[m]};
            a0 += cf * (h16x2){pr[0], pr[1]};
            a1 += cf * (h16x2){pr[2], pr[3]};
            a2_ += cf * (h16x2){pr[4], pr[5]};
            a3 += cf * (h16x2){pr[6], pr[7]};
          }
          if (pq == 64) { a3 = (h16x2){0, 0}; }
          if (pq == 65) { a0 = a1 = a2_ = a3 = (h16x2){0, 0}; }
          h16x8 o = {a0[0], a0[1], a1[0], a1[1], a2_[0], a2_[1], a3[0], a3[1]};
          *(h16x8*)(wsh + obase + (size_t)h * PITP + 8 * pq) = o;
          const float l0 = (float)a0[0], l1 = (float)a1[0];
          const float l2 = (float)a2_[0], l3 = (float)a3[0];
          const float g0 = (float)a0[1], g1 = (float)a1[1];
          const float g2 = (float)a2_[1], g3 = (float)a3[1];
          if (pq < 65) {
            const float m01 = fmaxf(l0, l1);
            const float m23 = (pq == 64) ? l2 : fmaxf(l2, l3);
            rowm = fmaxf(rowm, fmaxf(m01, m23));
            rowsum += l0 + l1 + l2 + l3;
          }
          if (pass == 0) {
            c0m[0] = fmaxf(c0m[0], g0); c0s[0] += g0;
            c0m[1] = fmaxf(c0m[1], g1); c0s[1] += g1;
            c0m[2] = fmaxf(c0m[2], g2); c0s[2] += g2;
            c0m[3] = fmaxf(c0m[3], g3); c0s[3] += g3;
          } else {
            c1m[0] = fmaxf(c1m[0], g0); c1s[0] += g0;
            c1m[1] = fmaxf(c1m[1], g1); c1s[1] += g1;
            c1m[2] = fmaxf(c1m[2], g2); c1s[2] += g2;
            c1m[3] = fmaxf(c1m[3], g3); c1s[3] += g3;
          }
        }
      }
#pragma unroll
      for (int off = 32; off; off >>= 1) {
        rowm = fmaxf(rowm, __shfl_xor(rowm, off));
        rowsum += __shfl_xor(rowsum, off);
      }
      if (lane == 0) {
        rsM[bc * 264 + h] = rowm;
        rsS[bc * 264 + h] = rowsum;
      }
    }
    __syncthreads();   // protect ring slots before next iteration's loads
  }

  // final: combine per-wave column stats (reuse ring LDS as f32 scratch)
  float* wbuf = (float*)sad;
  float* wm = wbuf + wave * 528;
  float* wsv = wm + 264;
#pragma unroll
  for (int k = 0; k < 4; ++k) { wm[4 * lane + k] = c0m[k]; wsv[4 * lane + k] = c0s[k]; }
  if (lane < 2) {
#pragma unroll
    for (int k = 0; k < 4; ++k) {
      wm[256 + 4 * lane + k] = c1m[k]; wsv[256 + 4 * lane + k] = c1s[k];
    }
  }
  __syncthreads();
  if (tid < 264) {
    float m = -3.4e38f, s = 0.f;
#pragma unroll
    for (int w8 = 0; w8 < 8; ++w8) {
      m = fmaxf(m, wbuf[w8 * 528 + tid]);
      s += wbuf[w8 * 528 + 264 + tid];
    }
    const size_t cb = ((size_t)bc * 2 + half) * 264 + tid;
    cpM[cb] = m; cpS[cb] = s;
  }
}

// =====================================================================
// Kernel 2: finish gates from stats only. Writes (sigmoid(y) - 1).
// =====================================================================
__global__ __launch_bounds__(256) void k_gate(
    const float* __restrict__ stat, float* __restrict__ gout,
    const float* lc1w, const float* lc1b, const float* lc2w,
    const float* lg, const float* lb, const float* lm, const float* lv,
    const float* hc1w, const float* hc1b, const float* hc2w,
    const float* hg, const float* hb, const float* hm, const float* hv) {
  __shared__ float cmx[264], csm[264], y0a[264], y0b[264];
  const int bc = blockIdx.x;
  const int tid = threadIdx.x;
  const float* rsM = stat;
  const float* rsS = stat + (size_t)N_IMG * 264;
  const float* cpM = rsS + (size_t)N_IMG * 264;
  const float* cpS = cpM + (size_t)N_IMG * 2 * 264;

  for (int col = tid; col < 264; col += 256) {
    const size_t cb0 = ((size_t)bc * 2) * 264 + col;
    const size_t cb1 = ((size_t)bc * 2 + 1) * 264 + col;
    cmx[col] = fmaxf(cpM[cb0], cpM[cb1]);
    csm[col] = cpS[cb0] + cpS[cb1];
  }
  __syncthreads();
  const float lw0 = lc1w[0], lw1 = lc1w[1], lbb0 = lc1b[0];
  const float hw0 = hc1w[0], hw1 = hc1w[1], hbb0 = hc1b[0];
  for (int idx = tid; idx < NC; idx += 256) {
    y0a[idx] = lw0 * rsM[bc * 264 + idx] + lw1 * (rsS[bc * 264 + idx] * (1.f / NC)) + lbb0;
    y0b[idx] = hw0 * cmx[idx] + hw1 * (csm[idx] * (1.f / NC)) + hbb0;
  }
  __syncthreads();
  const int c = bc & (C_CH - 1);
  const float lk0 = lc2w[c * 3], lk1 = lc2w[c * 3 + 1], lk2 = lc2w[c * 3 + 2];
  const float hk0 = hc2w[c * 3], hk1 = hc2w[c * 3 + 1], hk2 = hc2w[c * 3 + 2];
  const float lsc = rsqrtf(lv[c] + 1e-5f) * lg[c], lmu = lm[c], lbe = lb[c];
  const float hsc = rsqrtf(hv[c] + 1e-5f) * hg[c], hmu = hm[c], hbe = hb[c];
  for (int idx = tid; idx < NC; idx += 256) {
    float a = idx > 0 ? y0a[idx - 1] : 0.f;
    float b = y0a[idx];
    float d = idx < NC - 1 ? y0a[idx + 1] : 0.f;
    float y = lk0 * a + lk1 * b + lk2 * d;
    y = (y - lmu) * lsc + lbe;
    gout[(size_t)bc * GPIT + idx] = 1.f / (1.f + expf(-y)) - 1.f;

    a = idx > 0 ? y0b[idx - 1] : 0.f;
    b = y0b[idx];
    d = idx < NC - 1 ? y0b[idx + 1] : 0.f;
    y = hk0 * a + hk1 * b + hk2 * d;
    y = (y - hmu) * hsc + hbe;
    gout[(size_t)N_IMG * GPIT + (size_t)bc * GPIT + idx] = 1.f / (1.f + expf(-y)) - 1.f;
  }
}

// =====================================================================
// Kernel 3: out = 2x + IDWT(0,(g-1)LH,(g'-1)HL,0). 32-row strips in two
// 16-row batches sharing one 19-row staged buffer (halo 1.19x).
// =====================================================================
__global__ __launch_bounds__(512) void k_inv(const h16* __restrict__ wsh,
                                             const float* __restrict__ gbuf,
                                             const float* __restrict__ x,
                                             float* __restrict__ out) {
  __shared__ h16 sBC[19 * PITP];   // 20,064 B: gated pairs
  __shared__ h16 ad2[16 * PITP];   // 16,896 B: per-batch (a, g'.d)
  __shared__ h16 sghl16[264];
  // bijective XCD swizzle: nwg = 8192 = 8 * 1024
  const int p = blockIdx.x;
  const int w = (p & 7) * 1024 + (p >> 3);
  const int bc = w >> 4;               // 16 strips of 32 output rows
  const int t0 = (w & 15) * 32;
  const int u0 = t0 >> 1;              // subband rows u0..u0+18 (<=258)
  const int tid = threadIdx.x;
  const h16* sub = wsh + (size_t)bc * S2;
  const float* glh = gbuf + (size_t)bc * GPIT;
  const float* ghl = gbuf + (size_t)N_IMG * GPIT + (size_t)bc * GPIT;

  if (tid < 264) sghl16[tid] = (h16)ghl[tid];

  // stage 19 rows of {gl*LH, HL} pairs
  for (int t = tid; t < 19 * 66; t += 512) {
    const int j = t / 66, pq = t - j * 66;
    const int u = u0 + j;
    const h16 glH = (h16)glh[u];
    const h16x2 cf = {glH, (h16)1.0f};
    const h16x8 pr = *(const h16x8*)(sub + (size_t)u * PITP + 8 * pq);
    h16x2 r0 = cf * (h16x2){pr[0], pr[1]};
    h16x2 r1 = cf * (h16x2){pr[2], pr[3]};
    h16x2 r2 = cf * (h16x2){pr[4], pr[5]};
    h16x2 r3 = cf * (h16x2){pr[6], pr[7]};
    h16x8 o = {r0[0], r0[1], r1[0], r1[1], r2[0], r2[1], r3[0], r3[1]};
    *(h16x8*)(sBC + j * PITP + 8 * pq) = o;
  }
  __syncthreads();

#pragma unroll
  for (int batch = 0; batch < 2; ++batch) {
    // packed column IDWT for 16 rows of this batch
    for (int task = tid; task < 16 * 132; task += 512) {
      const int dtl = task / 132, pq = task - dtl * 132;
      const int dt = batch * 16 + dtl;
      const int par = dt & 1, lj0 = dt >> 1;
      h16x2 acc0 = {0, 0}, acc1 = {0, 0};
#pragma unroll
      for (int jj = 0; jj < 4; ++jj) {
        const int lj = lj0 + 3 - jj;
        const h16x2 cf = {(h16)(par ? RHI[1 + 2 * jj] : RHI[2 * jj]),
                          (h16)(par ? RLO[1 + 2 * jj] : RLO[2 * jj])};
        const h16x4 pr = *(const h16x4*)(sBC + lj * PITP + 4 * pq);
        acc0 += cf * (h16x2){pr[0], pr[1]};
        acc1 += cf * (h16x2){pr[2], pr[3]};
      }
      const h16x2 g2 = *(const h16x2*)(sghl16 + 2 * pq);
      const h16x2 cg0 = {(h16)1.0f, g2[0]};
      const h16x2 cg1 = {(h16)1.0f, g2[1]};
      acc0 *= cg0; acc1 *= cg1;
      h16x4 o = {acc0[0], acc0[1], acc1[0], acc1[1]};
      *(h16x4*)(ad2 + dtl * PITP + 4 * pq) = o;
    }
    __syncthreads();

    // row IDWT via fdot2 + out = 2x + corr (nontemporal x/out)
    for (int task = tid; task < 16 * 128; task += 512) {
      const int dtl = task >> 7, r = task & 127;
      const h16* row = ad2 + dtl * PITP + 4 * r;
      const h16x4 w0 = *(const h16x4*)(row);
      const h16x4 w1 = *(const h16x4*)(row + 4);
      const h16x2 w2 = *(const h16x2*)(row + 8);
      const h16x2 P[5] = {{w0[0], w0[1]}, {w0[2], w0[3]},
                          {w1[0], w1[1]}, {w1[2], w1[3]}, w2};
      float vv[4];
#pragma unroll
      for (int k = 0; k < 4; ++k) {
        const int base = k >> 1, par = k & 1;
        float s = 0.f;
#pragma unroll
        for (int jj = 0; jj < 4; ++jj) {
          const h16x2 cf = {(h16)RLO[par + 2 * jj], (h16)RHI[par + 2 * jj]};
          s = FDOT2(P[base + 3 - jj], cf, s);
        }
        vv[k] = s;
      }
      const size_t orow =
          ((size_t)bc * H_IN + (size_t)(t0 + batch * 16 + dtl)) * W_IN + 4 * r;
      const f32x4 xv = __builtin_nontemporal_load((const f32x4*)(x + orow));
      f32x4 ov;
      ov.x = 2.f * xv.x + vv[0]; ov.y = 2.f * xv.y + vv[1];
      ov.z = 2.f * xv.z + vv[2]; ov.w = 2.f * xv.w + vv[3];
      __builtin_nontemporal_store(ov, (f32x4*)(out + orow));
    }
    if (batch == 0) __syncthreads();
  }
}

extern "C" void kernel_launch(void* const* d_in, const int* in_sizes, int n_in,
                              void* d_out, int out_size, void* d_ws, size_t ws_size,
                              hipStream_t stream) {
  const float* x = (const float*)d_in[0];
  h16* wsh = (h16*)d_ws;
  float* statf = (float*)(wsh + (size_t)N_IMG * S2);
  // stat layout: rsM[512*264] | rsS | cpM[512*2*264] | cpS | glh | ghl
  float* gbuf = statf + 2 * (size_t)N_IMG * 264 + 2 * (size_t)N_IMG * 2 * 264;
  float* out = (float*)d_out;

  k_fwd<<<dim3(1024), 512, 0, stream>>>(x, wsh, statf);
  k_gate<<<dim3(N_IMG), 256, 0, stream>>>(
      statf, gbuf,
      (const float*)d_in[1], (const float*)d_in[2], (const float*)d_in[3],
      (const float*)d_in[4], (const float*)d_in[5], (const float*)d_in[6], (const float*)d_in[7],
      (const float*)d_in[8], (const float*)d_in[9], (const float*)d_in[10],
      (const float*)d_in[11], (const float*)d_in[12], (const float*)d_in[13], (const float*)d_in[14]);
  k_inv<<<dim3(16 * N_IMG), 512, 0, stream>>>(wsh, gbuf, x, out);
}

// Round 11
// 382.941 us; speedup vs baseline: 1.1210x; 1.1210x over previous
//
#include <hip/hip_runtime.h>

typedef _Float16 h16;
typedef _Float16 h16x2 __attribute__((ext_vector_type(2)));
typedef _Float16 h16x4 __attribute__((ext_vector_type(4)));
typedef _Float16 h16x8 __attribute__((ext_vector_type(8)));
typedef float f32x4 __attribute__((ext_vector_type(4)));

#if __has_builtin(__builtin_amdgcn_fdot2)
#define FDOT2(a, b, c) __builtin_amdgcn_fdot2((a), (b), (c), false)
#else
static __device__ __forceinline__ float FDOT2(h16x2 a, h16x2 b, float c) {
  return c + (float)a[0] * (float)b[0] + (float)a[1] * (float)b[1];
}
#endif

// ---- problem constants ----
#define N_IMG 512      // B*C = 8*64
#define C_CH  64
#define H_IN  512
#define W_IN  512
#define NC    259      // subband extent
#define PITP  528      // h16 per interleaved row: 264 (LH,HL)/(A,D) pairs
#define S2    ((size_t)NC * PITP)   // h16 per image (interleaved subband pair)
#define GPIT  264
#define FSTRIP 17      // k_fwd: 17 strips of 16 subband rows
#define LROWS  38      // x-rows per strip: 2*16+6

constexpr float DLO[8] = {
  -0.010597401784997278f,  0.032883011666982945f,  0.030841381835986965f, -0.18703481171888114f,
  -0.02798376941698385f,   0.6308807679295904f,    0.7148465705525415f,    0.23037781330885523f};
constexpr float DHI[8] = {
  -0.23037781330885523f,   0.7148465705525415f,   -0.6308807679295904f,   -0.02798376941698385f,
   0.18703481171888114f,   0.030841381835986965f, -0.032883011666982945f, -0.010597401784997278f};
constexpr float RLO[8] = {
   0.23037781330885523f,   0.7148465705525415f,    0.6308807679295904f,   -0.02798376941698385f,
  -0.18703481171888114f,   0.030841381835986965f,  0.032883011666982945f, -0.010597401784997278f};
constexpr float RHI[8] = {
  -0.010597401784997278f, -0.032883011666982945f,  0.030841381835986965f,  0.18703481171888114f,
  -0.02798376941698385f,  -0.6308807679295904f,    0.7148465705525415f,   -0.23037781330885523f};

// =====================================================================
// Kernel 1 (Round-9 form, measured): row DWT (f32) -> interleaved fp16
// (A,D) LDS -> packed-fp16 column DWT -> interleaved (LH,HL) global +
// fused gate stats.
// =====================================================================
__global__ __launch_bounds__(512) void k_fwd(const float* __restrict__ x,
                                             h16* __restrict__ wsh,
                                             float* __restrict__ stat) {
  __shared__ h16 sad[LROWS * PITP];          // 40,128 B -> 4 blocks/CU
  // bijective XCD swizzle: nwg = 8704 = 8 * 1088
  const int p = blockIdx.x;
  const int w = (p & 7) * 1088 + (p >> 3);
  const int bc = w / FSTRIP;
  const int bx = w - bc * FSTRIP;
  const int h0 = bx * 16;
  const int hcount = min(16, NC - h0);
  const int nrows = 2 * hcount + 6;
  const int tid = threadIdx.x;
  const int wave = tid >> 6, lane = tid & 63;
  const float* xim = x + (size_t)bc * (H_IN * (size_t)W_IN);

  // Phase A: row DWT (f32 math), store interleaved fp16 pairs
  for (int j = wave; j < nrows; j += 8) {
    int r = 2 * h0 - 6 + j;
    r = r < 0 ? -r - 1 : (r >= H_IN ? 2 * H_IN - 1 - r : r);
    const float* xrow = xim + (size_t)r * W_IN;
    h16* sj = sad + j * PITP;
    const int base = lane ? 8 * lane - 8 : 0;
    const float4 q0 = *(const float4*)(xrow + base);
    const float4 q1 = *(const float4*)(xrow + base + 4);
    const float4 q2 = *(const float4*)(xrow + base + 8);
    const float4 q3 = *(const float4*)(xrow + base + 12);
    const float v[16] = {q0.x, q0.y, q0.z, q0.w, q1.x, q1.y, q1.z, q1.w,
                         q2.x, q2.y, q2.z, q2.w, q3.x, q3.y, q3.z, q3.w};
    if (lane == 0) {
      h16x8 o;
#pragma unroll
      for (int i = 0; i < 4; ++i) {
        float a = 0.f, d = 0.f;
#pragma unroll
        for (int m = 0; m < 8; ++m) {
          int pp = 2 * i + 1 - m; pp = pp < 0 ? -pp - 1 : pp;
          const float t = v[pp];
          a += DLO[m] * t; d += DHI[m] * t;
        }
        o[2 * i] = (h16)a; o[2 * i + 1] = (h16)d;
      }
      *(h16x8*)(sj) = o;
    } else {
      h16x8 o;
#pragma unroll
      for (int k = 0; k < 4; ++k) {
        float a = 0.f, d = 0.f;
#pragma unroll
        for (int m = 0; m < 8; ++m) {
          const float t = v[2 * k + 9 - m];
          a += DLO[m] * t; d += DHI[m] * t;
        }
        o[2 * k] = (h16)a; o[2 * k + 1] = (h16)d;
      }
      *(h16x8*)(sj + 8 * lane) = o;
      if (lane == 63) {
#pragma unroll
        for (int i = 256; i < 259; ++i) {
          float a = 0.f, d = 0.f;
#pragma unroll
          for (int m = 0; m < 8; ++m) {
            int pp = 2 * i + 1 - m; pp = pp >= 512 ? 1023 - pp : pp;
            const float t = v[pp - 496];
            a += DLO[m] * t; d += DHI[m] * t;
          }
          h16x2 o2; o2[0] = (h16)a; o2[1] = (h16)d;
          *(h16x2*)(sj + 2 * i) = o2;
        }
      }
    }
  }
  __syncthreads();

  // Phase B: packed column DWT -> interleaved (LH,HL) global
  const size_t obase = (size_t)bc * S2;
  const int ntask = hcount * 66;             // <= 1056
  float rlh[3][4], rhl[3][4];
#pragma unroll
  for (int slot = 0; slot < 3; ++slot) {
    const int task = tid + slot * 512;
    if (task < ntask) {
      const int dh = task / 66, pq = task - dh * 66;
      h16x2 a0 = {0, 0}, a1 = {0, 0}, a2_ = {0, 0}, a3 = {0, 0};
#pragma unroll
      for (int m = 0; m < 8; ++m) {
        const int j = 2 * dh + 7 - m;
        const h16x8 pr = *(const h16x8*)(sad + j * PITP + 8 * pq);
        const h16x2 cf = {(h16)DHI[m], (h16)DLO[m]};
        const h16x2 p0 = {pr[0], pr[1]}, p1 = {pr[2], pr[3]};
        const h16x2 p2 = {pr[4], pr[5]}, p3 = {pr[6], pr[7]};
        a0 += cf * p0; a1 += cf * p1; a2_ += cf * p2; a3 += cf * p3;
      }
      if (pq == 64) { a3 = (h16x2){0, 0}; }
      if (pq == 65) { a0 = a1 = a2_ = a3 = (h16x2){0, 0}; }
      h16x8 o = {a0[0], a0[1], a1[0], a1[1], a2_[0], a2_[1], a3[0], a3[1]};
      *(h16x8*)(wsh + obase + (size_t)(h0 + dh) * PITP + 8 * pq) = o;
      rlh[slot][0] = (float)a0[0]; rlh[slot][1] = (float)a1[0];
      rlh[slot][2] = (float)a2_[0]; rlh[slot][3] = (float)a3[0];
      rhl[slot][0] = (float)a0[1]; rhl[slot][1] = (float)a1[1];
      rhl[slot][2] = (float)a2_[1]; rhl[slot][3] = (float)a3[1];
    }
  }
  __syncthreads();

  // Phase C: gate stats; reuse sad as f32 scratch
  float* scol = (float*)sad;                 // [16][264]
  float* prmx = scol + 16 * 264;             // [1056]
  float* prsm = prmx + 1056;                 // [1056]
#pragma unroll
  for (int slot = 0; slot < 3; ++slot) {
    const int task = tid + slot * 512;
    if (task < ntask) {
      const int dh = task / 66, pq = task - dh * 66;
      if (pq < 66) {
        *(float4*)(scol + dh * 264 + 4 * pq) =
            {rhl[slot][0], rhl[slot][1], rhl[slot][2], rhl[slot][3]};
      }
      if (pq == 65) {
        prmx[task] = -3.4e38f; prsm[task] = 0.f;
      } else {
        const float m01 = fmaxf(rlh[slot][0], rlh[slot][1]);
        const float m23 = (pq == 64) ? rlh[slot][2] : fmaxf(rlh[slot][2], rlh[slot][3]);
        prmx[task] = fmaxf(m01, m23);
        prsm[task] = rlh[slot][0] + rlh[slot][1] + rlh[slot][2] + rlh[slot][3];
      }
    }
  }
  __syncthreads();
  float* rsM = stat;
  float* rsS = stat + (size_t)N_IMG * 264;
  float* cpM = rsS + (size_t)N_IMG * 264;
  float* cpS = cpM + (size_t)N_IMG * FSTRIP * 264;
  for (int hh = wave; hh < hcount; hh += 8) {
    float m = prmx[hh * 66 + lane], s = prsm[hh * 66 + lane];
    if (lane == 0) {
      m = fmaxf(m, fmaxf(prmx[hh * 66 + 64], prmx[hh * 66 + 65]));
      s += prsm[hh * 66 + 64] + prsm[hh * 66 + 65];
    }
#pragma unroll
    for (int off = 32; off; off >>= 1) {
      m = fmaxf(m, __shfl_xor(m, off)); s += __shfl_xor(s, off);
    }
    if (lane == 0) {
      rsM[bc * 264 + h0 + hh] = m;
      rsS[bc * 264 + h0 + hh] = s;
    }
  }
  if (tid < 264) {
    float m = -3.4e38f, s = 0.f;
    for (int dh = 0; dh < hcount; ++dh) {
      const float vv = scol[dh * 264 + tid]; m = fmaxf(m, vv); s += vv;
    }
    const size_t cb = ((size_t)bc * FSTRIP + bx) * 264 + tid;
    cpM[cb] = m; cpS[cb] = s;
  }
}

// =====================================================================
// Kernel 2: finish gates from stats only. Writes (sigmoid(y) - 1).
// =====================================================================
__global__ __launch_bounds__(256) void k_gate(
    const float* __restrict__ stat, float* __restrict__ gout,
    const float* lc1w, const float* lc1b, const float* lc2w,
    const float* lg, const float* lb, const float* lm, const float* lv,
    const float* hc1w, const float* hc1b, const float* hc2w,
    const float* hg, const float* hb, const float* hm, const float* hv) {
  __shared__ float cmx[264], csm[264], y0a[264], y0b[264];
  const int bc = blockIdx.x;
  const int tid = threadIdx.x;
  const float* rsM = stat;
  const float* rsS = stat + (size_t)N_IMG * 264;
  const float* cpM = rsS + (size_t)N_IMG * 264;
  const float* cpS = cpM + (size_t)N_IMG * FSTRIP * 264;

  for (int col = tid; col < 264; col += 256) {
    float m = -3.4e38f, s = 0.f;
    for (int st = 0; st < FSTRIP; ++st) {
      const size_t cb = ((size_t)bc * FSTRIP + st) * 264 + col;
      m = fmaxf(m, cpM[cb]); s += cpS[cb];
    }
    cmx[col] = m; csm[col] = s;
  }
  __syncthreads();
  const float lw0 = lc1w[0], lw1 = lc1w[1], lbb0 = lc1b[0];
  const float hw0 = hc1w[0], hw1 = hc1w[1], hbb0 = hc1b[0];
  for (int idx = tid; idx < NC; idx += 256) {
    y0a[idx] = lw0 * rsM[bc * 264 + idx] + lw1 * (rsS[bc * 264 + idx] * (1.f / NC)) + lbb0;
    y0b[idx] = hw0 * cmx[idx] + hw1 * (csm[idx] * (1.f / NC)) + hbb0;
  }
  __syncthreads();
  const int c = bc & (C_CH - 1);
  const float lk0 = lc2w[c * 3], lk1 = lc2w[c * 3 + 1], lk2 = lc2w[c * 3 + 2];
  const float hk0 = hc2w[c * 3], hk1 = hc2w[c * 3 + 1], hk2 = hc2w[c * 3 + 2];
  const float lsc = rsqrtf(lv[c] + 1e-5f) * lg[c], lmu = lm[c], lbe = lb[c];
  const float hsc = rsqrtf(hv[c] + 1e-5f) * hg[c], hmu = hm[c], hbe = hb[c];
  for (int idx = tid; idx < NC; idx += 256) {
    float a = idx > 0 ? y0a[idx - 1] : 0.f;
    float b = y0a[idx];
    float d = idx < NC - 1 ? y0a[idx + 1] : 0.f;
    float y = lk0 * a + lk1 * b + lk2 * d;
    y = (y - lmu) * lsc + lbe;
    gout[(size_t)bc * GPIT + idx] = 1.f / (1.f + expf(-y)) - 1.f;

    a = idx > 0 ? y0b[idx - 1] : 0.f;
    b = y0b[idx];
    d = idx < NC - 1 ? y0b[idx + 1] : 0.f;
    y = hk0 * a + hk1 * b + hk2 * d;
    y = (y - hmu) * hsc + hbe;
    gout[(size_t)N_IMG * GPIT + (size_t)bc * GPIT + idx] = 1.f / (1.f + expf(-y)) - 1.f;
  }
}

// =====================================================================
// Kernel 3 (Round-10 form): out = 2x + IDWT(0,(g-1)LH,(g'-1)HL,0).
// 32-row strips in two 16-row batches sharing one 19-row staged buffer.
// =====================================================================
__global__ __launch_bounds__(512) void k_inv(const h16* __restrict__ wsh,
                                             const float* __restrict__ gbuf,
                                             const float* __restrict__ x,
                                             float* __restrict__ out) {
  __shared__ h16 sBC[19 * PITP];   // 20,064 B: gated pairs
  __shared__ h16 ad2[16 * PITP];   // 16,896 B: per-batch (a, g'.d)
  __shared__ h16 sghl16[264];
  // bijective XCD swizzle: nwg = 8192 = 8 * 1024
  const int p = blockIdx.x;
  const int w = (p & 7) * 1024 + (p >> 3);
  const int bc = w >> 4;               // 16 strips of 32 output rows
  const int t0 = (w & 15) * 32;
  const int u0 = t0 >> 1;              // subband rows u0..u0+18 (<=258)
  const int tid = threadIdx.x;
  const h16* sub = wsh + (size_t)bc * S2;
  const float* glh = gbuf + (size_t)bc * GPIT;
  const float* ghl = gbuf + (size_t)N_IMG * GPIT + (size_t)bc * GPIT;

  if (tid < 264) sghl16[tid] = (h16)ghl[tid];

  // stage 19 rows of {gl*LH, HL} pairs
  for (int t = tid; t < 19 * 66; t += 512) {
    const int j = t / 66, pq = t - j * 66;
    const int u = u0 + j;
    const h16 glH = (h16)glh[u];
    const h16x2 cf = {glH, (h16)1.0f};
    const h16x8 pr = *(const h16x8*)(sub + (size_t)u * PITP + 8 * pq);
    h16x2 r0 = cf * (h16x2){pr[0], pr[1]};
    h16x2 r1 = cf * (h16x2){pr[2], pr[3]};
    h16x2 r2 = cf * (h16x2){pr[4], pr[5]};
    h16x2 r3 = cf * (h16x2){pr[6], pr[7]};
    h16x8 o = {r0[0], r0[1], r1[0], r1[1], r2[0], r2[1], r3[0], r3[1]};
    *(h16x8*)(sBC + j * PITP + 8 * pq) = o;
  }
  __syncthreads();

#pragma unroll
  for (int batch = 0; batch < 2; ++batch) {
    // packed column IDWT for 16 rows of this batch
    for (int task = tid; task < 16 * 132; task += 512) {
      const int dtl = task / 132, pq = task - dtl * 132;
      const int dt = batch * 16 + dtl;
      const int par = dt & 1, lj0 = dt >> 1;
      h16x2 acc0 = {0, 0}, acc1 = {0, 0};
#pragma unroll
      for (int jj = 0; jj < 4; ++jj) {
        const int lj = lj0 + 3 - jj;
        const h16x2 cf = {(h16)(par ? RHI[1 + 2 * jj] : RHI[2 * jj]),
                          (h16)(par ? RLO[1 + 2 * jj] : RLO[2 * jj])};
        const h16x4 pr = *(const h16x4*)(sBC + lj * PITP + 4 * pq);
        acc0 += cf * (h16x2){pr[0], pr[1]};
        acc1 += cf * (h16x2){pr[2], pr[3]};
      }
      const h16x2 g2 = *(const h16x2*)(sghl16 + 2 * pq);
      const h16x2 cg0 = {(h16)1.0f, g2[0]};
      const h16x2 cg1 = {(h16)1.0f, g2[1]};
      acc0 *= cg0; acc1 *= cg1;
      h16x4 o = {acc0[0], acc0[1], acc1[0], acc1[1]};
      *(h16x4*)(ad2 + dtl * PITP + 4 * pq) = o;
    }
    __syncthreads();

    // row IDWT via fdot2 + out = 2x + corr (nontemporal x/out)
    for (int task = tid; task < 16 * 128; task += 512) {
      const int dtl = task >> 7, r = task & 127;
      const h16* row = ad2 + dtl * PITP + 4 * r;
      const h16x4 w0 = *(const h16x4*)(row);
      const h16x4 w1 = *(const h16x4*)(row + 4);
      const h16x2 w2 = *(const h16x2*)(row + 8);
      const h16x2 P[5] = {{w0[0], w0[1]}, {w0[2], w0[3]},
                          {w1[0], w1[1]}, {w1[2], w1[3]}, w2};
      float vv[4];
#pragma unroll
      for (int k = 0; k < 4; ++k) {
        const int base = k >> 1, par = k & 1;
        float s = 0.f;
#pragma unroll
        for (int jj = 0; jj < 4; ++jj) {
          const h16x2 cf = {(h16)RLO[par + 2 * jj], (h16)RHI[par + 2 * jj]};
          s = FDOT2(P[base + 3 - jj], cf, s);
        }
        vv[k] = s;
      }
      const size_t orow =
          ((size_t)bc * H_IN + (size_t)(t0 + batch * 16 + dtl)) * W_IN + 4 * r;
      const f32x4 xv = __builtin_nontemporal_load((const f32x4*)(x + orow));
      f32x4 ov;
      ov.x = 2.f * xv.x + vv[0]; ov.y = 2.f * xv.y + vv[1];
      ov.z = 2.f * xv.z + vv[2]; ov.w = 2.f * xv.w + vv[3];
      __builtin_nontemporal_store(ov, (f32x4*)(out + orow));
    }
    if (batch == 0) __syncthreads();
  }
}

extern "C" void kernel_launch(void* const* d_in, const int* in_sizes, int n_in,
                              void* d_out, int out_size, void* d_ws, size_t ws_size,
                              hipStream_t stream) {
  const float* x = (const float*)d_in[0];
  h16* wsh = (h16*)d_ws;
  float* statf = (float*)(wsh + (size_t)N_IMG * S2);
  // stat layout: rsM[512*264] | rsS | cpM[512*17*264] | cpS | glh | ghl
  float* gbuf = statf + 2 * (size_t)N_IMG * 264 + 2 * (size_t)N_IMG * FSTRIP * 264;
  float* out = (float*)d_out;

  k_fwd<<<dim3(FSTRIP * N_IMG), 512, 0, stream>>>(x, wsh, statf);
  k_gate<<<dim3(N_IMG), 256, 0, stream>>>(
      statf, gbuf,
      (const float*)d_in[1], (const float*)d_in[2], (const float*)d_in[3],
      (const float*)d_in[4], (const float*)d_in[5], (const float*)d_in[6], (const float*)d_in[7],
      (const float*)d_in[8], (const float*)d_in[9], (const float*)d_in[10],
      (const float*)d_in[11], (const float*)d_in[12], (const float*)d_in[13], (const float*)d_in[14]);
  k_inv<<<dim3(16 * N_IMG), 512, 0, stream>>>(wsh, gbuf, x, out);
}

// Round 12
// 369.521 us; speedup vs baseline: 1.1617x; 1.0363x over previous
//
#include <hip/hip_runtime.h>

typedef _Float16 h16;
typedef _Float16 h16x2 __attribute__((ext_vector_type(2)));
typedef _Float16 h16x4 __attribute__((ext_vector_type(4)));
typedef _Float16 h16x8 __attribute__((ext_vector_type(8)));
typedef float f32x4 __attribute__((ext_vector_type(4)));

#if __has_builtin(__builtin_amdgcn_fdot2)
#define FDOT2(a, b, c) __builtin_amdgcn_fdot2((a), (b), (c), false)
#else
static __device__ __forceinline__ float FDOT2(h16x2 a, h16x2 b, float c) {
  return c + (float)a[0] * (float)b[0] + (float)a[1] * (float)b[1];
}
#endif

// ---- problem constants ----
#define N_IMG 512      // B*C = 8*64
#define C_CH  64
#define H_IN  512
#define W_IN  512
#define NC    259      // subband extent
#define PITP  528      // h16 per interleaved row: 264 (LH,HL)/(A,D) pairs
#define S2    ((size_t)NC * PITP)   // h16 per image (interleaved subband pair)
#define GPIT  264
#define FSTRIP 17      // k_fwd: 17 strips of 16 subband rows
#define LROWS  38      // x-rows per strip: 2*16+6

constexpr float DLO[8] = {
  -0.010597401784997278f,  0.032883011666982945f,  0.030841381835986965f, -0.18703481171888114f,
  -0.02798376941698385f,   0.6308807679295904f,    0.7148465705525415f,    0.23037781330885523f};
constexpr float DHI[8] = {
  -0.23037781330885523f,   0.7148465705525415f,   -0.6308807679295904f,   -0.02798376941698385f,
   0.18703481171888114f,   0.030841381835986965f, -0.032883011666982945f, -0.010597401784997278f};
constexpr float RLO[8] = {
   0.23037781330885523f,   0.7148465705525415f,    0.6308807679295904f,   -0.02798376941698385f,
  -0.18703481171888114f,   0.030841381835986965f,  0.032883011666982945f, -0.010597401784997278f};
constexpr float RHI[8] = {
  -0.010597401784997278f, -0.032883011666982945f,  0.030841381835986965f,  0.18703481171888114f,
  -0.02798376941698385f,  -0.6308807679295904f,    0.7148465705525415f,   -0.23037781330885523f};

// =====================================================================
// Kernel 1: row DWT (f32) -> interleaved fp16 (A,D) LDS -> packed-fp16
// column DWT -> interleaved (LH,HL) global + fused gate stats.
// =====================================================================
__global__ __launch_bounds__(512) void k_fwd(const float* __restrict__ x,
                                             h16* __restrict__ wsh,
                                             float* __restrict__ stat) {
  __shared__ h16 sad[LROWS * PITP];          // 40,128 B -> 4 blocks/CU
  // bijective XCD swizzle: nwg = 8704 = 8 * 1088
  const int p = blockIdx.x;
  const int w = (p & 7) * 1088 + (p >> 3);
  const int bc = w / FSTRIP;
  const int bx = w - bc * FSTRIP;
  const int h0 = bx * 16;
  const int hcount = min(16, NC - h0);
  const int nrows = 2 * hcount + 6;
  const int tid = threadIdx.x;
  const int wave = tid >> 6, lane = tid & 63;
  const float* xim = x + (size_t)bc * (H_IN * (size_t)W_IN);

  // Phase A: row DWT (f32 math), store interleaved fp16 pairs
  for (int j = wave; j < nrows; j += 8) {
    int r = 2 * h0 - 6 + j;
    r = r < 0 ? -r - 1 : (r >= H_IN ? 2 * H_IN - 1 - r : r);
    const float* xrow = xim + (size_t)r * W_IN;
    h16* sj = sad + j * PITP;
    const int base = lane ? 8 * lane - 8 : 0;
    const float4 q0 = *(const float4*)(xrow + base);
    const float4 q1 = *(const float4*)(xrow + base + 4);
    const float4 q2 = *(const float4*)(xrow + base + 8);
    const float4 q3 = *(const float4*)(xrow + base + 12);
    const float v[16] = {q0.x, q0.y, q0.z, q0.w, q1.x, q1.y, q1.z, q1.w,
                         q2.x, q2.y, q2.z, q2.w, q3.x, q3.y, q3.z, q3.w};
    if (lane == 0) {
      h16x8 o;
#pragma unroll
      for (int i = 0; i < 4; ++i) {
        float a = 0.f, d = 0.f;
#pragma unroll
        for (int m = 0; m < 8; ++m) {
          int pp = 2 * i + 1 - m; pp = pp < 0 ? -pp - 1 : pp;
          const float t = v[pp];
          a += DLO[m] * t; d += DHI[m] * t;
        }
        o[2 * i] = (h16)a; o[2 * i + 1] = (h16)d;
      }
      *(h16x8*)(sj) = o;
    } else {
      h16x8 o;
#pragma unroll
      for (int k = 0; k < 4; ++k) {
        float a = 0.f, d = 0.f;
#pragma unroll
        for (int m = 0; m < 8; ++m) {
          const float t = v[2 * k + 9 - m];
          a += DLO[m] * t; d += DHI[m] * t;
        }
        o[2 * k] = (h16)a; o[2 * k + 1] = (h16)d;
      }
      *(h16x8*)(sj + 8 * lane) = o;
      if (lane == 63) {
#pragma unroll
        for (int i = 256; i < 259; ++i) {
          float a = 0.f, d = 0.f;
#pragma unroll
          for (int m = 0; m < 8; ++m) {
            int pp = 2 * i + 1 - m; pp = pp >= 512 ? 1023 - pp : pp;
            const float t = v[pp - 496];
            a += DLO[m] * t; d += DHI[m] * t;
          }
          h16x2 o2; o2[0] = (h16)a; o2[1] = (h16)d;
          *(h16x2*)(sj + 2 * i) = o2;
        }
      }
    }
  }
  __syncthreads();

  // Phase B: packed column DWT -> interleaved (LH,HL) global
  const size_t obase = (size_t)bc * S2;
  const int ntask = hcount * 66;             // <= 1056
  float rlh[3][4], rhl[3][4];
#pragma unroll
  for (int slot = 0; slot < 3; ++slot) {
    const int task = tid + slot * 512;
    if (task < ntask) {
      const int dh = task / 66, pq = task - dh * 66;
      h16x2 a0 = {0, 0}, a1 = {0, 0}, a2_ = {0, 0}, a3 = {0, 0};
#pragma unroll
      for (int m = 0; m < 8; ++m) {
        const int j = 2 * dh + 7 - m;
        const h16x8 pr = *(const h16x8*)(sad + j * PITP + 8 * pq);
        const h16x2 cf = {(h16)DHI[m], (h16)DLO[m]};
        const h16x2 p0 = {pr[0], pr[1]}, p1 = {pr[2], pr[3]};
        const h16x2 p2 = {pr[4], pr[5]}, p3 = {pr[6], pr[7]};
        a0 += cf * p0; a1 += cf * p1; a2_ += cf * p2; a3 += cf * p3;
      }
      if (pq == 64) { a3 = (h16x2){0, 0}; }
      if (pq == 65) { a0 = a1 = a2_ = a3 = (h16x2){0, 0}; }
      h16x8 o = {a0[0], a0[1], a1[0], a1[1], a2_[0], a2_[1], a3[0], a3[1]};
      *(h16x8*)(wsh + obase + (size_t)(h0 + dh) * PITP + 8 * pq) = o;
      rlh[slot][0] = (float)a0[0]; rlh[slot][1] = (float)a1[0];
      rlh[slot][2] = (float)a2_[0]; rlh[slot][3] = (float)a3[0];
      rhl[slot][0] = (float)a0[1]; rhl[slot][1] = (float)a1[1];
      rhl[slot][2] = (float)a2_[1]; rhl[slot][3] = (float)a3[1];
    }
  }
  __syncthreads();

  // Phase C: gate stats; reuse sad as f32 scratch
  float* scol = (float*)sad;                 // [16][264]
  float* prmx = scol + 16 * 264;             // [1056]
  float* prsm = prmx + 1056;                 // [1056]
#pragma unroll
  for (int slot = 0; slot < 3; ++slot) {
    const int task = tid + slot * 512;
    if (task < ntask) {
      const int dh = task / 66, pq = task - dh * 66;
      if (pq < 66) {
        *(float4*)(scol + dh * 264 + 4 * pq) =
            {rhl[slot][0], rhl[slot][1], rhl[slot][2], rhl[slot][3]};
      }
      if (pq == 65) {
        prmx[task] = -3.4e38f; prsm[task] = 0.f;
      } else {
        const float m01 = fmaxf(rlh[slot][0], rlh[slot][1]);
        const float m23 = (pq == 64) ? rlh[slot][2] : fmaxf(rlh[slot][2], rlh[slot][3]);
        prmx[task] = fmaxf(m01, m23);
        prsm[task] = rlh[slot][0] + rlh[slot][1] + rlh[slot][2] + rlh[slot][3];
      }
    }
  }
  __syncthreads();
  float* rsM = stat;
  float* rsS = stat + (size_t)N_IMG * 264;
  float* cpM = rsS + (size_t)N_IMG * 264;
  float* cpS = cpM + (size_t)N_IMG * FSTRIP * 264;
  for (int hh = wave; hh < hcount; hh += 8) {
    float m = prmx[hh * 66 + lane], s = prsm[hh * 66 + lane];
    if (lane == 0) {
      m = fmaxf(m, fmaxf(prmx[hh * 66 + 64], prmx[hh * 66 + 65]));
      s += prsm[hh * 66 + 64] + prsm[hh * 66 + 65];
    }
#pragma unroll
    for (int off = 32; off; off >>= 1) {
      m = fmaxf(m, __shfl_xor(m, off)); s += __shfl_xor(s, off);
    }
    if (lane == 0) {
      rsM[bc * 264 + h0 + hh] = m;
      rsS[bc * 264 + h0 + hh] = s;
    }
  }
  if (tid < 264) {
    float m = -3.4e38f, s = 0.f;
    for (int dh = 0; dh < hcount; ++dh) {
      const float vv = scol[dh * 264 + tid]; m = fmaxf(m, vv); s += vv;
    }
    const size_t cb = ((size_t)bc * FSTRIP + bx) * 264 + tid;
    cpM[cb] = m; cpS[cb] = s;
  }
}

// =====================================================================
// Kernel 2: finish gates from stats only. Writes (sigmoid(y) - 1).
// =====================================================================
__global__ __launch_bounds__(256) void k_gate(
    const float* __restrict__ stat, float* __restrict__ gout,
    const float* lc1w, const float* lc1b, const float* lc2w,
    const float* lg, const float* lb, const float* lm, const float* lv,
    const float* hc1w, const float* hc1b, const float* hc2w,
    const float* hg, const float* hb, const float* hm, const float* hv) {
  __shared__ float cmx[264], csm[264], y0a[264], y0b[264];
  const int bc = blockIdx.x;
  const int tid = threadIdx.x;
  const float* rsM = stat;
  const float* rsS = stat + (size_t)N_IMG * 264;
  const float* cpM = rsS + (size_t)N_IMG * 264;
  const float* cpS = cpM + (size_t)N_IMG * FSTRIP * 264;

  for (int col = tid; col < 264; col += 256) {
    float m = -3.4e38f, s = 0.f;
    for (int st = 0; st < FSTRIP; ++st) {
      const size_t cb = ((size_t)bc * FSTRIP + st) * 264 + col;
      m = fmaxf(m, cpM[cb]); s += cpS[cb];
    }
    cmx[col] = m; csm[col] = s;
  }
  __syncthreads();
  const float lw0 = lc1w[0], lw1 = lc1w[1], lbb0 = lc1b[0];
  const float hw0 = hc1w[0], hw1 = hc1w[1], hbb0 = hc1b[0];
  for (int idx = tid; idx < NC; idx += 256) {
    y0a[idx] = lw0 * rsM[bc * 264 + idx] + lw1 * (rsS[bc * 264 + idx] * (1.f / NC)) + lbb0;
    y0b[idx] = hw0 * cmx[idx] + hw1 * (csm[idx] * (1.f / NC)) + hbb0;
  }
  __syncthreads();
  const int c = bc & (C_CH - 1);
  const float lk0 = lc2w[c * 3], lk1 = lc2w[c * 3 + 1], lk2 = lc2w[c * 3 + 2];
  const float hk0 = hc2w[c * 3], hk1 = hc2w[c * 3 + 1], hk2 = hc2w[c * 3 + 2];
  const float lsc = rsqrtf(lv[c] + 1e-5f) * lg[c], lmu = lm[c], lbe = lb[c];
  const float hsc = rsqrtf(hv[c] + 1e-5f) * hg[c], hmu = hm[c], hbe = hb[c];
  for (int idx = tid; idx < NC; idx += 256) {
    float a = idx > 0 ? y0a[idx - 1] : 0.f;
    float b = y0a[idx];
    float d = idx < NC - 1 ? y0a[idx + 1] : 0.f;
    float y = lk0 * a + lk1 * b + lk2 * d;
    y = (y - lmu) * lsc + lbe;
    gout[(size_t)bc * GPIT + idx] = 1.f / (1.f + expf(-y)) - 1.f;

    a = idx > 0 ? y0b[idx - 1] : 0.f;
    b = y0b[idx];
    d = idx < NC - 1 ? y0b[idx + 1] : 0.f;
    y = hk0 * a + hk1 * b + hk2 * d;
    y = (y - hmu) * hsc + hbe;
    gout[(size_t)N_IMG * GPIT + (size_t)bc * GPIT + idx] = 1.f / (1.f + expf(-y)) - 1.f;
  }
}

// =====================================================================
// Kernel 3: out = 2x + IDWT(0,(g-1)LH,(g'-1)HL,0). 16-row strips,
// packed-fp16 staging + column IDWT, fdot2 row IDWT, NT x/out.
// =====================================================================
__global__ __launch_bounds__(512) void k_inv(const h16* __restrict__ wsh,
                                             const float* __restrict__ gbuf,
                                             const float* __restrict__ x,
                                             float* __restrict__ out) {
  __shared__ h16 sBC[11 * PITP];   // 11,616 B: 11 rows of gated pairs
  __shared__ h16 ad2[16 * PITP];   // 16,896 B: (a, g'.d) pairs
  __shared__ h16 sghl16[264];
  // bijective XCD swizzle: nwg = 16384 = 8 * 2048
  const int p = blockIdx.x;
  const int w = (p & 7) * 2048 + (p >> 3);
  const int bc = w >> 5;               // 32 strips of 16 output rows
  const int t0 = (w & 31) * 16;
  const int u0 = t0 >> 1;              // subband rows u0..u0+10 (<=258)
  const int tid = threadIdx.x;
  const h16* sub = wsh + (size_t)bc * S2;
  const float* glh = gbuf + (size_t)bc * GPIT;
  const float* ghl = gbuf + (size_t)N_IMG * GPIT + (size_t)bc * GPIT;

  if (tid < 264) sghl16[tid] = (h16)ghl[tid];

  // stage 11 rows of {gl*LH, HL} pairs (pk_mul by {gl,1})
  for (int t = tid; t < 11 * 66; t += 512) {
    const int j = t / 66, pq = t - j * 66;
    const int u = u0 + j;
    const h16 glH = (h16)glh[u];
    const h16x2 cf = {glH, (h16)1.0f};
    const h16x8 pr = *(const h16x8*)(sub + (size_t)u * PITP + 8 * pq);
    h16x2 r0 = cf * (h16x2){pr[0], pr[1]};
    h16x2 r1 = cf * (h16x2){pr[2], pr[3]};
    h16x2 r2 = cf * (h16x2){pr[4], pr[5]};
    h16x2 r3 = cf * (h16x2){pr[6], pr[7]};
    h16x8 o = {r0[0], r0[1], r1[0], r1[1], r2[0], r2[1], r3[0], r3[1]};
    *(h16x8*)(sBC + j * PITP + 8 * pq) = o;
  }
  __syncthreads();

  // packed column IDWT: acc pair {a, d} = sum {rh,rl}*{glLH, HL}; then {1,ghl}
  for (int task = tid; task < 16 * 132; task += 512) {
    const int dt = task / 132, pq = task - dt * 132;
    const int par = dt & 1, lj0 = dt >> 1;
    h16x2 acc0 = {0, 0}, acc1 = {0, 0};
#pragma unroll
    for (int jj = 0; jj < 4; ++jj) {
      const int lj = lj0 + 3 - jj;
      const h16x2 cf = {(h16)(par ? RHI[1 + 2 * jj] : RHI[2 * jj]),
                        (h16)(par ? RLO[1 + 2 * jj] : RLO[2 * jj])};
      const h16x4 pr = *(const h16x4*)(sBC + lj * PITP + 4 * pq);
      acc0 += cf * (h16x2){pr[0], pr[1]};
      acc1 += cf * (h16x2){pr[2], pr[3]};
    }
    const h16x2 g2 = *(const h16x2*)(sghl16 + 2 * pq);
    const h16x2 cg0 = {(h16)1.0f, g2[0]};
    const h16x2 cg1 = {(h16)1.0f, g2[1]};
    acc0 *= cg0; acc1 *= cg1;
    h16x4 o = {acc0[0], acc0[1], acc1[0], acc1[1]};
    *(h16x4*)(ad2 + dt * PITP + 4 * pq) = o;
  }
  __syncthreads();

  // row IDWT via fdot2 + out = 2x + corr (nontemporal x/out)
  for (int task = tid; task < 16 * 128; task += 512) {
    const int dt = task >> 7, r = task & 127;
    const h16* row = ad2 + dt * PITP + 4 * r;       // pair q=2r at h16 idx 4r
    const h16x4 w0 = *(const h16x4*)(row);
    const h16x4 w1 = *(const h16x4*)(row + 4);
    const h16x2 w2 = *(const h16x2*)(row + 8);
    const h16x2 P[5] = {{w0[0], w0[1]}, {w0[2], w0[3]},
                        {w1[0], w1[1]}, {w1[2], w1[3]}, w2};
    float vv[4];
#pragma unroll
    for (int k = 0; k < 4; ++k) {
      const int base = k >> 1, par = k & 1;
      float s = 0.f;
#pragma unroll
      for (int jj = 0; jj < 4; ++jj) {
        const h16x2 cf = {(h16)RLO[par + 2 * jj], (h16)RHI[par + 2 * jj]};
        s = FDOT2(P[base + 3 - jj], cf, s);
      }
      vv[k] = s;
    }
    const size_t orow = ((size_t)bc * H_IN + (size_t)(t0 + dt)) * W_IN + 4 * r;
    const f32x4 xv = __builtin_nontemporal_load((const f32x4*)(x + orow));
    f32x4 ov;
    ov.x = 2.f * xv.x + vv[0]; ov.y = 2.f * xv.y + vv[1];
    ov.z = 2.f * xv.z + vv[2]; ov.w = 2.f * xv.w + vv[3];
    __builtin_nontemporal_store(ov, (f32x4*)(out + orow));
  }
}

extern "C" void kernel_launch(void* const* d_in, const int* in_sizes, int n_in,
                              void* d_out, int out_size, void* d_ws, size_t ws_size,
                              hipStream_t stream) {
  const float* x = (const float*)d_in[0];
  h16* wsh = (h16*)d_ws;
  float* statf = (float*)(wsh + (size_t)N_IMG * S2);
  // stat layout: rsM[512*264] | rsS | cpM[512*17*264] | cpS | glh | ghl
  float* gbuf = statf + 2 * (size_t)N_IMG * 264 + 2 * (size_t)N_IMG * FSTRIP * 264;
  float* out = (float*)d_out;

  k_fwd<<<dim3(FSTRIP * N_IMG), 512, 0, stream>>>(x, wsh, statf);
  k_gate<<<dim3(N_IMG), 256, 0, stream>>>(
      statf, gbuf,
      (const float*)d_in[1], (const float*)d_in[2], (const float*)d_in[3],
      (const float*)d_in[4], (const float*)d_in[5], (const float*)d_in[6], (const float*)d_in[7],
      (const float*)d_in[8], (const float*)d_in[9], (const float*)d_in[10],
      (const float*)d_in[11], (const float*)d_in[12], (const float*)d_in[13], (const float*)d_in[14]);
  k_inv<<<dim3(32 * N_IMG), 512, 0, stream>>>(wsh, gbuf, x, out);
}